// Round 1
// baseline (247.451 us; speedup 1.0000x reference)
//
#include <hip/hip_runtime.h>
#include <hip/hip_bf16.h>

typedef _Float16 half8 __attribute__((ext_vector_type(8)));
typedef _Float16 half4v __attribute__((ext_vector_type(4)));
typedef _Float16 half2v __attribute__((ext_vector_type(2)));
typedef float f32x4 __attribute__((ext_vector_type(4)));

static __device__ __forceinline__ f32x4 mfma16(half8 a, half8 b, f32x4 c) {
    return __builtin_amdgcn_mfma_f32_16x16x32_f16(a, b, c, 0, 0, 0);
}

// ---------------------------------------------------------------------------
// prep: pack weights into MFMA fragment order (fp16), written to ws.
// A-frag layout for mfma_f32_16x16x32: lane l holds row (l&15), k=(l>>4)*8+j.
// kappa(f,g,j) = 16*(2f + (j>>2)) + 4g + (j&3)  -- the D-slot -> B-frag map.
// ---------------------------------------------------------------------------
__global__ __launch_bounds__(256) void prep_kernel(
    const float* __restrict__ mqw1, const float* __restrict__ mkw1,
    const float* __restrict__ mqw2, const float* __restrict__ mkw2,
    const float* __restrict__ caw1, const float* __restrict__ caw2,
    _Float16* __restrict__ ApackConv, _Float16* __restrict__ ApackW2s,
    _Float16* __restrict__ ApackCA, _Float16* __restrict__ ApackW2K4)
{
    int tid = threadIdx.x;
    // conv3x3 weights: [br][kstep(18)][mf(4)][lane(64)][j(8)], k = tap*64 + ic
    for (int idx = tid; idx < 73728; idx += 256) {
        int j = idx & 7, lane = (idx >> 3) & 63, mf = (idx >> 9) & 3;
        int ks18 = idx >> 11;
        int br = ks18 / 18, kstep = ks18 % 18;
        int oc = mf * 16 + (lane & 15);
        int g = lane >> 4;
        int k = kstep * 32 + g * 8 + j;
        int tap = k >> 6, ic = k & 63;
        int dy = tap / 3, dx = tap - dy * 3;
        const float* w1 = br ? mkw1 : mqw1;
        ApackConv[idx] = (_Float16)w1[((oc * 64 + ic) * 3 + dy) * 3 + dx];
    }
    // 1x1 (64->8) weights, kappa-permuted, rows 8..15 zero: [br][f(2)][lane][j]
    for (int idx = tid; idx < 2048; idx += 256) {
        int j = idx & 7, lane = (idx >> 3) & 63;
        int f = (idx >> 9) & 1, br = idx >> 10;
        int dc = lane & 15, g = lane >> 4;
        int kap = 16 * (2 * f + (j >> 2)) + 4 * g + (j & 3);
        const float* w2 = br ? mkw2 : mqw2;
        ApackW2s[idx] = (_Float16)((dc < 8) ? w2[dc * 64 + kap] : 0.f);
    }
    // ca_w1, kappa-permuted: [f(2)][mf(4)][lane][j]
    for (int idx = tid; idx < 4096; idx += 256) {
        int j = idx & 7, lane = (idx >> 3) & 63, mf = (idx >> 9) & 3, f = idx >> 11;
        int cp = mf * 16 + (lane & 15), g = lane >> 4;
        int kap = 16 * (2 * f + (j >> 2)) + 4 * g + (j & 3);
        ApackCA[idx] = (_Float16)caw1[cp * 64 + kap];
    }
    // ca_w2, linear k: [f(2)][mf(4)][lane][j]
    for (int idx = tid; idx < 4096; idx += 256) {
        int j = idx & 7, lane = (idx >> 3) & 63, mf = (idx >> 9) & 3, f = idx >> 11;
        int cc = mf * 16 + (lane & 15), g = lane >> 4;
        int cpk = f * 32 + g * 8 + j;
        ApackW2K4[idx] = (_Float16)caw2[cc * 64 + cpk];
    }
}

// ---------------------------------------------------------------------------
// K1: conv3x3(mask)+b1 -> relu -> 1x1(->8)+b2, for both q and k branches.
// Block = 4 rows x 64 px; wave w owns row y0+w. MFMA implicit GEMM.
// ---------------------------------------------------------------------------
__global__ __launch_bounds__(256) void conv_mask_kernel(
    const float* __restrict__ mask,
    const _Float16* __restrict__ ApackConv,
    const _Float16* __restrict__ ApackW2s,
    const float* __restrict__ mqb1, const float* __restrict__ mqb2,
    const float* __restrict__ mkb1, const float* __restrict__ mkb2,
    float* __restrict__ maskq, float* __restrict__ maskk)
{
    __shared__ _Float16 tile[25344]; // [ic/8][r(6)][c(66)][ic&7]
    int tid = threadIdx.x;
    int lane = tid & 63, w = tid >> 6;
    int x0 = blockIdx.x * 64, y0 = blockIdx.y * 4, b = blockIdx.z;

    for (int idx = tid; idx < 25344; idx += 256) {
        int c = idx % 66;
        int t2 = idx / 66;
        int r = t2 % 6;
        int ic = t2 / 6;
        int y = y0 - 1 + r, xx = x0 - 1 + c;
        float v = 0.f;
        if (y >= 0 && y < 128 && xx >= 0 && xx < 128)
            v = mask[((size_t)(b * 64 + ic) * 128 + y) * 128 + xx];
        tile[(((ic >> 3) * 6 + r) * 66 + c) * 8 + (ic & 7)] = (_Float16)v;
    }
    __syncthreads();

    int q = lane & 15, g = lane >> 4;
#pragma unroll 1
    for (int br = 0; br < 2; br++) {
        f32x4 acc[4][4] = {};
        const _Float16* Ab = ApackConv + br * 36864;
        for (int kstep = 0; kstep < 18; kstep++) {
            int tap = kstep >> 1;
            int dyv = tap / 3, dxv = tap - dyv * 3;
            int ich = (kstep & 1) * 4 + g;
            half8 bf[4];
#pragma unroll
            for (int nf = 0; nf < 4; nf++) {
                int cc = q + nf * 16 + dxv;
                bf[nf] = *(const half8*)&tile[((ich * 6 + (w + dyv)) * 66 + cc) * 8];
            }
            const _Float16* Ak = Ab + kstep * 2048 + lane * 8;
#pragma unroll
            for (int mf = 0; mf < 4; mf++) {
                half8 af = *(const half8*)(Ak + mf * 512);
#pragma unroll
                for (int nf = 0; nf < 4; nf++)
                    acc[mf][nf] = mfma16(af, bf[nf], acc[mf][nf]);
            }
        }
        // epilogue: relu(t + b1) -> 1x1 via MFMA (kappa repack, register-local)
        const float* b1p = br ? mkb1 : mqb1;
        const float* b2p = br ? mkb2 : mqb2;
        float* outp = br ? maskk : maskq;
        float b1v[16];
#pragma unroll
        for (int mf = 0; mf < 4; mf++)
#pragma unroll
            for (int r = 0; r < 4; r++) b1v[mf * 4 + r] = b1p[mf * 16 + g * 4 + r];
        f32x4 acc2[4] = {};
#pragma unroll
        for (int f = 0; f < 2; f++) {
            half8 a2 = *(const half8*)(ApackW2s + (br * 2 + f) * 512 + lane * 8);
#pragma unroll
            for (int nf = 0; nf < 4; nf++) {
                half8 b2;
#pragma unroll
                for (int j = 0; j < 8; j++) {
                    int mfj = 2 * f + (j >> 2), rj = j & 3;
                    b2[j] = (_Float16)fmaxf(acc[mfj][nf][rj] + b1v[mfj * 4 + rj], 0.f);
                }
                acc2[nf] = mfma16(a2, b2, acc2[nf]);
            }
        }
        if (g < 2) {
            int y = y0 + w;
#pragma unroll
            for (int r = 0; r < 4; r++) {
                int dc = g * 4 + r;
                float bb = b2p[dc];
#pragma unroll
                for (int nf = 0; nf < 4; nf++)
                    outp[((size_t)(b * 8 + dc) * 128 + y) * 128 + (x0 + nf * 16 + q)] =
                        acc2[nf][r] + bb;
            }
        }
    }
}

// ---------------------------------------------------------------------------
// K2: Q/K = avgpool2x2( (alpha*mask_qk + 1-alpha) * (Wqk x + b) )  [fp32]
//     V = Wv * avgpool2x2(x) + bv                                   [fp16]
// One block per (batch, pooled row).
// ---------------------------------------------------------------------------
__global__ __launch_bounds__(256) void proj_kernel(
    const float* __restrict__ xg,
    const float* __restrict__ maskq, const float* __restrict__ maskk,
    const float* __restrict__ Wq, const float* __restrict__ bq,
    const float* __restrict__ Wk, const float* __restrict__ bk,
    const float* __restrict__ Wv, const float* __restrict__ bv,
    const float* __restrict__ a1p, const float* __restrict__ a2p,
    float* __restrict__ Qg, float* __restrict__ Kg, _Float16* __restrict__ Vg)
{
    __shared__ float xr[16384]; // [ic][ysel][x]
    __shared__ float xp[4096];  // [ic][j] pooled
    int tid = threadIdx.x;
    int b = blockIdx.x >> 6, i = blockIdx.x & 63;

    for (int idx = tid; idx < 16384; idx += 256) {
        int ic = idx >> 8, rem = idx & 255;
        xr[idx] = xg[((size_t)(b * 64 + ic) * 128 + (2 * i + (rem >> 7))) * 128 + (rem & 127)];
    }
    __syncthreads();
    for (int idx = tid; idx < 4096; idx += 256) {
        int ic = idx >> 6, j = idx & 63;
        const float* base = &xr[ic * 256 + 2 * j];
        xp[idx] = 0.25f * (base[0] + base[1] + base[128] + base[129]);
    }
    __syncthreads();

    // V
    {
        int c0 = tid >> 5;
        int jp = tid & 31;
        int j0 = jp * 2;
        float acc0[8], acc1[8];
#pragma unroll
        for (int u = 0; u < 8; u++) { float bb = bv[c0 + 8 * u]; acc0[u] = bb; acc1[u] = bb; }
        for (int ic = 0; ic < 64; ic++) {
            float x0v = xp[ic * 64 + j0], x1v = xp[ic * 64 + j0 + 1];
#pragma unroll
            for (int u = 0; u < 8; u++) {
                float ww = Wv[(c0 + 8 * u) * 64 + ic];
                acc0[u] += ww * x0v; acc1[u] += ww * x1v;
            }
        }
#pragma unroll
        for (int u = 0; u < 8; u++) {
            int c = c0 + 8 * u;
            half2v hv = { (_Float16)acc0[u], (_Float16)acc1[u] };
            *(half2v*)(Vg + (size_t)(b * 64 + c) * 4096 + i * 64 + j0) = hv;
        }
    }
    // Q / K
    {
        int branch = tid >> 7;
        int ysel = tid & 1;
        int j = (tid >> 1) & 63;
        const float* W = branch ? Wk : Wq;
        const float* bias = branch ? bk : bq;
        float alpha = branch ? a2p[0] : a1p[0];
        const float* mq = branch ? maskk : maskq;
        float* outg = branch ? Kg : Qg;
        int x0c = 2 * j, x1c = 2 * j + 1;
        float aq0[8], aq1[8];
#pragma unroll
        for (int dc = 0; dc < 8; dc++) { float bb = bias[dc]; aq0[dc] = bb; aq1[dc] = bb; }
        for (int ic = 0; ic < 64; ic++) {
            float xv0 = xr[ic * 256 + ysel * 128 + x0c];
            float xv1 = xr[ic * 256 + ysel * 128 + x1c];
#pragma unroll
            for (int dc = 0; dc < 8; dc++) {
                float ww = W[dc * 64 + ic];
                aq0[dc] += ww * xv0; aq1[dc] += ww * xv1;
            }
        }
        int y = 2 * i + ysel;
#pragma unroll
        for (int dc = 0; dc < 8; dc++) {
            size_t mbase = ((size_t)(b * 8 + dc) * 128 + y) * 128;
            float m0v = mq[mbase + x0c], m1v = mq[mbase + x1c];
            float s = aq0[dc] * (alpha * m0v + (1.f - alpha))
                    + aq1[dc] * (alpha * m1v + (1.f - alpha));
            s += __shfl_xor(s, 1);
            if (ysel == 0) outg[(size_t)(b * 8 + dc) * 4096 + i * 64 + j] = 0.25f * s;
        }
    }
}

// ---------------------------------------------------------------------------
// K3: flash attention (N=4096, d=8, dv=64) fused with z = ca_w1*out + ca_b1.
// S^T = K·Q^T via MFMA (d zero-padded to 32): softmax state is lane-local
// (q = lane&15). PV: out^T[c][q] with P as B-operand (register-local repack).
// Block = 64 queries (4 waves x 16); loops 64 key tiles of 64.
// ---------------------------------------------------------------------------
__global__ __launch_bounds__(256) void attn_kernel(
    const float* __restrict__ Qg, const float* __restrict__ Kg,
    const _Float16* __restrict__ Vg,
    const _Float16* __restrict__ ApackCA, const float* __restrict__ cb1,
    float* __restrict__ zg)
{
    __shared__ _Float16 Klds[64 * 40]; // [s][40]: d 0..7 data, 8..39 zeros
    __shared__ _Float16 Vt[64 * 80];   // [c][80]: keys 0..63 (+pad)
    int tid = threadIdx.x;
    int lane = tid & 63, w = tid >> 6;
    int bid = blockIdx.x;
    int b = (bid & 7) >> 1;                      // XCD-friendly mapping
    int qt = ((bid >> 3) << 1) | (bid & 1);
    int m0 = qt * 64 + w * 16;
    int q = lane & 15, g = lane >> 4;

    for (int idx = tid; idx < 2048; idx += 256) {
        int s = idx >> 5, dcol = 8 + (idx & 31);
        Klds[s * 40 + dcol] = (_Float16)0.f;
    }
    half8 qf;
    if (g == 0) {
#pragma unroll
        for (int j = 0; j < 8; j++) qf[j] = (_Float16)Qg[(size_t)(b * 8 + j) * 4096 + m0 + q];
    } else {
#pragma unroll
        for (int j = 0; j < 8; j++) qf[j] = (_Float16)0.f;
    }
    f32x4 acc[4] = {};
    float m_run = -1e30f, l_run = 0.f;
    const f32x4 zero4 = {};

    for (int kt = 0; kt < 64; kt++) {
        int n0 = kt * 64;
        __syncthreads();
        {
            int s = tid & 63, d0 = tid >> 6;
#pragma unroll
            for (int dd = 0; dd < 2; dd++) {
                int d = d0 + dd * 4;
                Klds[s * 40 + d] = (_Float16)Kg[(size_t)(b * 8 + d) * 4096 + n0 + s];
            }
            int c = tid >> 2, seg = tid & 3;
            const half8* src = (const half8*)(Vg + (size_t)(b * 64 + c) * 4096 + n0 + seg * 16);
            half8 v0 = src[0], v1 = src[1];
            *(half8*)&Vt[c * 80 + seg * 16] = v0;
            *(half8*)&Vt[c * 80 + seg * 16 + 8] = v1;
        }
        __syncthreads();

        f32x4 st[4];
#pragma unroll
        for (int mf = 0; mf < 4; mf++) {
            half8 af = *(const half8*)&Klds[(mf * 16 + q) * 40 + g * 8];
            st[mf] = mfma16(af, qf, zero4);
        }
        float pm = -1e30f;
#pragma unroll
        for (int mf = 0; mf < 4; mf++)
#pragma unroll
            for (int r = 0; r < 4; r++) pm = fmaxf(pm, st[mf][r]);
        pm = fmaxf(pm, __shfl_xor(pm, 16));
        pm = fmaxf(pm, __shfl_xor(pm, 32));
        float mnew = fmaxf(m_run, pm);
        float p[16];
        float ls = 0.f;
#pragma unroll
        for (int mf = 0; mf < 4; mf++)
#pragma unroll
            for (int r = 0; r < 4; r++) {
                float e = __expf(st[mf][r] - mnew);
                p[mf * 4 + r] = e; ls += e;
            }
        ls += __shfl_xor(ls, 16);
        ls += __shfl_xor(ls, 32);
        float rr = __expf(m_run - mnew);
        l_run = l_run * rr + ls;
        m_run = mnew;
#pragma unroll
        for (int mf = 0; mf < 4; mf++) acc[mf] *= rr;

#pragma unroll
        for (int f = 0; f < 2; f++) {
            half8 pb;
#pragma unroll
            for (int j = 0; j < 8; j++)
                pb[j] = (_Float16)p[(2 * f + (j >> 2)) * 4 + (j & 3)];
#pragma unroll
            for (int mfc = 0; mfc < 4; mfc++) {
                int row = mfc * 16 + q;
                half4v a0 = *(const half4v*)&Vt[row * 80 + f * 32 + g * 4];
                half4v a1 = *(const half4v*)&Vt[row * 80 + f * 32 + 16 + g * 4];
                half8 av = __builtin_shufflevector(a0, a1, 0, 1, 2, 3, 4, 5, 6, 7);
                acc[mfc] = mfma16(av, pb, acc[mfc]);
            }
        }
    }
    // finalize + fused z = ca_w1 * out_att + ca_b1
    float inv = 1.f / l_run;
    half8 ob[2];
#pragma unroll
    for (int f = 0; f < 2; f++)
#pragma unroll
        for (int j = 0; j < 8; j++)
            ob[f][j] = (_Float16)(acc[2 * f + (j >> 2)][j & 3] * inv);
    f32x4 zacc[4] = {};
#pragma unroll
    for (int f = 0; f < 2; f++)
#pragma unroll
        for (int mf2 = 0; mf2 < 4; mf2++) {
            half8 a3 = *(const half8*)(ApackCA + (f * 4 + mf2) * 512 + lane * 8);
            zacc[mf2] = mfma16(a3, ob[f], zacc[mf2]);
        }
#pragma unroll
    for (int mf2 = 0; mf2 < 4; mf2++)
#pragma unroll
        for (int r = 0; r < 4; r++) {
            int cp = mf2 * 16 + g * 4 + r;
            zg[(size_t)(b * 64 + cp) * 4096 + m0 + q] = zacc[mf2][r] + cb1[cp];
        }
}

// ---------------------------------------------------------------------------
// K4: out = ca_w2 * relu(upsample2x(z)) + ca_b2 + x.  Block = 4 rows x 64 px.
// ---------------------------------------------------------------------------
__global__ __launch_bounds__(256) void post_kernel(
    const float* __restrict__ zg, const float* __restrict__ xg,
    const _Float16* __restrict__ ApackW2K4, const float* __restrict__ cb2,
    float* __restrict__ outg)
{
    __shared__ float zt[4 * 34 * 68]; // [(r*34+col)*68 + c']
    int tid = threadIdx.x, lane = tid & 63, w = tid >> 6;
    int x0 = blockIdx.x * 64, y0 = blockIdx.y * 4, b = blockIdx.z;
    int r0 = 2 * (int)blockIdx.y - 1;
    int cbs = 32 * (int)blockIdx.x - 1;
    for (int idx = tid; idx < 8704; idx += 256) {
        int col = idx % 34;
        int t2 = idx / 34;
        int r = t2 & 3, cp = t2 >> 2;
        int zr = min(max(r0 + r, 0), 63);
        int zc = min(max(cbs + col, 0), 63);
        zt[(r * 34 + col) * 68 + cp] = zg[(size_t)(b * 64 + cp) * 4096 + zr * 64 + zc];
    }
    __syncthreads();

    int q = lane & 15, g = lane >> 4;
    int y = y0 + w;
    int ra = (w >> 1) + (w & 1);
    float wyA = (w & 1) ? 0.75f : 0.25f;
    float wyB = 1.f - wyA;
    f32x4 acc[4][4] = {};
#pragma unroll
    for (int f = 0; f < 2; f++) {
        half8 a[4];
#pragma unroll
        for (int mf = 0; mf < 4; mf++)
            a[mf] = *(const half8*)(ApackW2K4 + (f * 4 + mf) * 512 + lane * 8);
#pragma unroll
        for (int nf = 0; nf < 4; nf++) {
            int pxl = nf * 16 + q;
            int ca = (pxl >> 1) + (pxl & 1);
            float wxA = (pxl & 1) ? 0.75f : 0.25f;
            float wxB = 1.f - wxA;
            half8 bfrag;
#pragma unroll
            for (int qd = 0; qd < 2; qd++) {
                int cpb = f * 32 + g * 8 + qd * 4;
                const float* z00 = &zt[(ra * 34 + ca) * 68 + cpb];
                f32x4 v00 = *(const f32x4*)z00;
                f32x4 v01 = *(const f32x4*)(z00 + 68);
                f32x4 v10 = *(const f32x4*)(z00 + 34 * 68);
                f32x4 v11 = *(const f32x4*)(z00 + 34 * 68 + 68);
                f32x4 zu = (v00 * wxA + v01 * wxB) * wyA + (v10 * wxA + v11 * wxB) * wyB;
#pragma unroll
                for (int e = 0; e < 4; e++) bfrag[qd * 4 + e] = (_Float16)fmaxf(zu[e], 0.f);
            }
#pragma unroll
            for (int mf = 0; mf < 4; mf++) acc[mf][nf] = mfma16(a[mf], bfrag, acc[mf][nf]);
        }
    }
#pragma unroll
    for (int mf = 0; mf < 4; mf++)
#pragma unroll
        for (int r = 0; r < 4; r++) {
            int c = mf * 16 + g * 4 + r;
            float bb = cb2[c];
#pragma unroll
            for (int nf = 0; nf < 4; nf++) {
                size_t oidx = ((size_t)(b * 64 + c) * 128 + y) * 128 + x0 + nf * 16 + q;
                outg[oidx] = acc[mf][nf][r] + bb + xg[oidx];
            }
        }
}

// ---------------------------------------------------------------------------
extern "C" void kernel_launch(void* const* d_in, const int* in_sizes, int n_in,
                              void* d_out, int out_size, void* d_ws, size_t ws_size,
                              hipStream_t stream)
{
    const float* x    = (const float*)d_in[0];
    const float* mask = (const float*)d_in[1];
    const float* Wq   = (const float*)d_in[2];
    const float* bq   = (const float*)d_in[3];
    const float* Wk   = (const float*)d_in[4];
    const float* bk   = (const float*)d_in[5];
    const float* Wv   = (const float*)d_in[6];
    const float* bv   = (const float*)d_in[7];
    const float* a1   = (const float*)d_in[8];
    const float* a2   = (const float*)d_in[9];
    const float* mqw1 = (const float*)d_in[10];
    const float* mqb1 = (const float*)d_in[11];
    const float* mqw2 = (const float*)d_in[12];
    const float* mqb2 = (const float*)d_in[13];
    const float* mkw1 = (const float*)d_in[14];
    const float* mkb1 = (const float*)d_in[15];
    const float* mkw2 = (const float*)d_in[16];
    const float* mkb2 = (const float*)d_in[17];
    const float* caw1 = (const float*)d_in[18];
    const float* cab1 = (const float*)d_in[19];
    const float* caw2 = (const float*)d_in[20];
    const float* cab2 = (const float*)d_in[21];

    char* ws = (char*)d_ws;
    _Float16* ApackConv = (_Float16*)(ws + 0);
    _Float16* ApackW2s  = (_Float16*)(ws + 147456);
    _Float16* ApackCA   = (_Float16*)(ws + 151552);
    _Float16* ApackW2K4 = (_Float16*)(ws + 159744);
    float*    maskq     = (float*)(ws + 196608);
    float*    maskk     = (float*)(ws + 196608 + 2097152);
    float*    Qb        = (float*)(ws + 196608 + 2 * 2097152);
    float*    Kb        = (float*)(ws + 196608 + 2 * 2097152 + 524288);
    _Float16* Vb        = (_Float16*)(ws + 196608 + 2 * 2097152 + 2 * 524288);
    float*    zb        = (float*)(ws + 196608 + 3 * 2097152 + 2 * 524288);

    prep_kernel<<<dim3(1), dim3(256), 0, stream>>>(
        mqw1, mkw1, mqw2, mkw2, caw1, caw2, ApackConv, ApackW2s, ApackCA, ApackW2K4);
    conv_mask_kernel<<<dim3(2, 32, 4), dim3(256), 0, stream>>>(
        mask, ApackConv, ApackW2s, mqb1, mqb2, mkb1, mkb2, maskq, maskk);
    proj_kernel<<<dim3(256), dim3(256), 0, stream>>>(
        x, maskq, maskk, Wq, bq, Wk, bk, Wv, bv, a1, a2, Qb, Kb, Vb);
    attn_kernel<<<dim3(256), dim3(256), 0, stream>>>(
        Qb, Kb, Vb, ApackCA, cab1, zb);
    post_kernel<<<dim3(2, 32, 4), dim3(256), 0, stream>>>(
        zb, x, ApackW2K4, cab2, (float*)d_out);
}

// Round 2
// 113.559 us; speedup vs baseline: 2.1790x; 2.1790x over previous
//
#include <hip/hip_runtime.h>
#include <hip/hip_bf16.h>

typedef _Float16 half8 __attribute__((ext_vector_type(8)));
typedef _Float16 half4v __attribute__((ext_vector_type(4)));
typedef float f32x4 __attribute__((ext_vector_type(4)));

static __device__ __forceinline__ f32x4 mfma16(half8 a, half8 b, f32x4 c) {
    return __builtin_amdgcn_mfma_f32_16x16x32_f16(a, b, c, 0, 0, 0);
}

typedef const __attribute__((address_space(1))) unsigned int* gas_ptr;
typedef __attribute__((address_space(3))) unsigned int* las_ptr;
static __device__ __forceinline__ void gload16(const void* g, void* l) {
    __builtin_amdgcn_global_load_lds((gas_ptr)g, (las_ptr)l, 16, 0, 0);
}

// ---------------- workspace layout (bytes) ----------------
#define WS_APCONV   0u          // 147456
#define WS_APW2S    147456u     // 4096
#define WS_APCA     151552u     // 8192
#define WS_APW2K4   159744u     // 8192
#define WS_PACKED   196608u     // 8,652,800   [b][8][130][130][8] f16
#define WS_MASKQ    8849408u    // 2,097,152   [b][8][128][128] f32
#define WS_MASKK    10946560u   // 2,097,152
#define WS_Q16      13043712u   // 262,144     [b][4096][8] f16
#define WS_K16      13305856u   // 262,144
#define WS_V16      13568000u   // 2,097,152   [b][64][4096] f16
#define WS_ZB       15665152u   // 4,194,304   [b][64][4096] f32
// overlays (live only during attn/combine, after packed/maskq done):
#define WS_PACC     196608u     // 8,388,608   [1024 tiles][64c][64q] f16
#define WS_PML      8585216u    // 524,288     [1024 tiles][m64|l64] f32

// ---------------------------------------------------------------------------
// prep: pack weights into MFMA fragment order (fp16). grid 64.
// ---------------------------------------------------------------------------
__global__ __launch_bounds__(256) void prep_kernel(
    const float* __restrict__ mqw1, const float* __restrict__ mkw1,
    const float* __restrict__ mqw2, const float* __restrict__ mkw2,
    const float* __restrict__ caw1, const float* __restrict__ caw2,
    _Float16* __restrict__ ApackConv, _Float16* __restrict__ ApackW2s,
    _Float16* __restrict__ ApackCA, _Float16* __restrict__ ApackW2K4)
{
    int tid0 = blockIdx.x * 256 + threadIdx.x;
    const int stride = 64 * 256;
    for (int idx = tid0; idx < 73728; idx += stride) {
        int j = idx & 7, lane = (idx >> 3) & 63, mf = (idx >> 9) & 3;
        int ks18 = idx >> 11;
        int br = ks18 / 18, kstep = ks18 % 18;
        int oc = mf * 16 + (lane & 15);
        int g = lane >> 4;
        int k = kstep * 32 + g * 8 + j;
        int tap = k >> 6, ic = k & 63;
        int dy = tap / 3, dx = tap - dy * 3;
        const float* w1 = br ? mkw1 : mqw1;
        ApackConv[idx] = (_Float16)w1[((oc * 64 + ic) * 3 + dy) * 3 + dx];
    }
    for (int idx = tid0; idx < 2048; idx += stride) {
        int j = idx & 7, lane = (idx >> 3) & 63;
        int f = (idx >> 9) & 1, br = idx >> 10;
        int dc = lane & 15, g = lane >> 4;
        int kap = 16 * (2 * f + (j >> 2)) + 4 * g + (j & 3);
        const float* w2 = br ? mkw2 : mqw2;
        ApackW2s[idx] = (_Float16)((dc < 8) ? w2[dc * 64 + kap] : 0.f);
    }
    for (int idx = tid0; idx < 4096; idx += stride) {
        int j = idx & 7, lane = (idx >> 3) & 63, mf = (idx >> 9) & 3, f = idx >> 11;
        int cp = mf * 16 + (lane & 15), g = lane >> 4;
        int kap = 16 * (2 * f + (j >> 2)) + 4 * g + (j & 3);
        ApackCA[idx] = (_Float16)caw1[cp * 64 + kap];
    }
    for (int idx = tid0; idx < 4096; idx += stride) {
        int j = idx & 7, lane = (idx >> 3) & 63, mf = (idx >> 9) & 3, f = idx >> 11;
        int cc = mf * 16 + (lane & 15), g = lane >> 4;
        int cpk = f * 32 + g * 8 + j;
        ApackW2K4[idx] = (_Float16)caw2[cc * 64 + cpk];
    }
}

// ---------------------------------------------------------------------------
// pack mask -> fp16 [b][ich=8][row 130][col 130][8ic], zero border (memset'd).
// grid (64 y-pairs, 8 ich, 4 b), 256 threads.
// ---------------------------------------------------------------------------
__global__ __launch_bounds__(256) void pack_mask_kernel(
    const float* __restrict__ mask, _Float16* __restrict__ packed)
{
    int x = threadIdx.x & 127;
    int sy = blockIdx.x * 2 + (threadIdx.x >> 7);
    int ich = blockIdx.y, b = blockIdx.z;
    half8 v;
#pragma unroll
    for (int cc = 0; cc < 8; cc++)
        v[cc] = (_Float16)mask[(((size_t)(b * 64 + ich * 8 + cc)) * 128 + sy) * 128 + x];
    *(half8*)(packed + ((((size_t)b * 8 + ich) * 130 + sy + 1) * 130 + (x + 1)) * 8) = v;
}

// ---------------------------------------------------------------------------
// K1: conv3x3(mask)+b1 -> relu -> 1x1(->8)+b2. No LDS: B-frags direct from
// packed global (L1-resident). Block = 4 rows x 64 cols, one branch.
// grid (2, 32, 8=b*2+br).
// ---------------------------------------------------------------------------
__global__ __launch_bounds__(256) void conv_mask_kernel(
    const _Float16* __restrict__ packed,
    const _Float16* __restrict__ ApackConv,
    const _Float16* __restrict__ ApackW2s,
    const float* __restrict__ mqb1, const float* __restrict__ mqb2,
    const float* __restrict__ mkb1, const float* __restrict__ mkb2,
    float* __restrict__ maskq, float* __restrict__ maskk)
{
    int tid = threadIdx.x;
    int lane = tid & 63, w = tid >> 6;
    int x0 = blockIdx.x * 64;
    int y = blockIdx.y * 4 + w;
    int bz = blockIdx.z;
    int b = bz >> 1, br = bz & 1;
    int q = lane & 15, g = lane >> 4;

    const _Float16* Ab = ApackConv + br * 36864;
    const _Float16* Pb = packed + (size_t)b * 8 * 130 * 130 * 8;

    f32x4 acc[4][4] = {};
    for (int kstep = 0; kstep < 18; kstep++) {
        int tap = kstep >> 1;
        int dyv = tap / 3, dxv = tap - dyv * 3;
        int ich = (kstep & 1) * 4 + g;
        const _Float16* prow = Pb + (((size_t)ich * 130 + (y + dyv)) * 130 + (x0 + q + dxv)) * 8;
        half8 bf[4];
#pragma unroll
        for (int nf = 0; nf < 4; nf++)
            bf[nf] = *(const half8*)(prow + nf * 128);
        const _Float16* Ak = Ab + kstep * 2048 + lane * 8;
#pragma unroll
        for (int mf = 0; mf < 4; mf++) {
            half8 af = *(const half8*)(Ak + mf * 512);
#pragma unroll
            for (int nf = 0; nf < 4; nf++)
                acc[mf][nf] = mfma16(af, bf[nf], acc[mf][nf]);
        }
    }
    const float* b1p = br ? mkb1 : mqb1;
    const float* b2p = br ? mkb2 : mqb2;
    float* outp = br ? maskk : maskq;
    float b1v[16];
#pragma unroll
    for (int mf = 0; mf < 4; mf++)
#pragma unroll
        for (int r = 0; r < 4; r++) b1v[mf * 4 + r] = b1p[mf * 16 + g * 4 + r];
    f32x4 acc2[4] = {};
#pragma unroll
    for (int f = 0; f < 2; f++) {
        half8 a2 = *(const half8*)(ApackW2s + (br * 2 + f) * 512 + lane * 8);
#pragma unroll
        for (int nf = 0; nf < 4; nf++) {
            half8 b2f;
#pragma unroll
            for (int j = 0; j < 8; j++) {
                int mfj = 2 * f + (j >> 2), rj = j & 3;
                b2f[j] = (_Float16)fmaxf(acc[mfj][nf][rj] + b1v[mfj * 4 + rj], 0.f);
            }
            acc2[nf] = mfma16(a2, b2f, acc2[nf]);
        }
    }
    if (g < 2) {
#pragma unroll
        for (int r = 0; r < 4; r++) {
            int dc = g * 4 + r;
            float bb = b2p[dc];
#pragma unroll
            for (int nf = 0; nf < 4; nf++)
                outp[((size_t)(b * 8 + dc) * 128 + y) * 128 + (x0 + nf * 16 + q)] =
                    acc2[nf][r] + bb;
        }
    }
}

// ---------------------------------------------------------------------------
// K2: Q/K = avgpool2x2((alpha*mask+1-alpha)*(W x + b)) -> f16 [b][n][8]
//     V = Wv * avgpool2x2(x) + bv -> f16 [b][c][n]
// ---------------------------------------------------------------------------
__global__ __launch_bounds__(256) void proj_kernel(
    const float* __restrict__ xg,
    const float* __restrict__ maskq, const float* __restrict__ maskk,
    const float* __restrict__ Wq, const float* __restrict__ bq,
    const float* __restrict__ Wk, const float* __restrict__ bk,
    const float* __restrict__ Wv, const float* __restrict__ bv,
    const float* __restrict__ a1p, const float* __restrict__ a2p,
    _Float16* __restrict__ Qg, _Float16* __restrict__ Kg, _Float16* __restrict__ Vg)
{
    __shared__ float xr[16384]; // [ic][ysel][x]
    __shared__ float xp[4096];  // [ic][j] pooled
    int tid = threadIdx.x;
    int b = blockIdx.x >> 6, i = blockIdx.x & 63;

    for (int idx = tid; idx < 16384; idx += 256) {
        int ic = idx >> 8, rem = idx & 255;
        xr[idx] = xg[((size_t)(b * 64 + ic) * 128 + (2 * i + (rem >> 7))) * 128 + (rem & 127)];
    }
    __syncthreads();
    for (int idx = tid; idx < 4096; idx += 256) {
        int ic = idx >> 6, j = idx & 63;
        const float* base = &xr[ic * 256 + 2 * j];
        xp[idx] = 0.25f * (base[0] + base[1] + base[128] + base[129]);
    }
    __syncthreads();

    // V
    {
        int c0 = tid >> 5;
        int j0 = (tid & 31) * 2;
        float acc0[8], acc1[8];
#pragma unroll
        for (int u = 0; u < 8; u++) { float bb = bv[c0 + 8 * u]; acc0[u] = bb; acc1[u] = bb; }
        for (int ic = 0; ic < 64; ic++) {
            float x0v = xp[ic * 64 + j0], x1v = xp[ic * 64 + j0 + 1];
#pragma unroll
            for (int u = 0; u < 8; u++) {
                float ww = Wv[(c0 + 8 * u) * 64 + ic];
                acc0[u] += ww * x0v; acc1[u] += ww * x1v;
            }
        }
#pragma unroll
        for (int u = 0; u < 8; u++) {
            int c = c0 + 8 * u;
            _Float16 h0 = (_Float16)acc0[u], h1 = (_Float16)acc1[u];
            _Float16* p = Vg + (size_t)(b * 64 + c) * 4096 + i * 64 + j0;
            p[0] = h0; p[1] = h1;
        }
    }
    // Q / K
    {
        int branch = tid >> 7;
        int ysel = tid & 1;
        int j = (tid >> 1) & 63;
        const float* W = branch ? Wk : Wq;
        const float* bias = branch ? bk : bq;
        float alpha = branch ? a2p[0] : a1p[0];
        const float* mq = branch ? maskk : maskq;
        _Float16* outg = branch ? Kg : Qg;
        int x0c = 2 * j, x1c = 2 * j + 1;
        float aq0[8], aq1[8];
#pragma unroll
        for (int dc = 0; dc < 8; dc++) { float bb = bias[dc]; aq0[dc] = bb; aq1[dc] = bb; }
        for (int ic = 0; ic < 64; ic++) {
            float xv0 = xr[ic * 256 + ysel * 128 + x0c];
            float xv1 = xr[ic * 256 + ysel * 128 + x1c];
#pragma unroll
            for (int dc = 0; dc < 8; dc++) {
                float ww = W[dc * 64 + ic];
                aq0[dc] += ww * xv0; aq1[dc] += ww * xv1;
            }
        }
        int yy = 2 * i + ysel;
        half8 vq;
#pragma unroll
        for (int dc = 0; dc < 8; dc++) {
            size_t mbase = ((size_t)(b * 8 + dc) * 128 + yy) * 128;
            float m0v = mq[mbase + x0c], m1v = mq[mbase + x1c];
            float s = aq0[dc] * (alpha * m0v + (1.f - alpha))
                    + aq1[dc] * (alpha * m1v + (1.f - alpha));
            s += __shfl_xor(s, 1);
            vq[dc] = (_Float16)(0.25f * s);
        }
        if (ysel == 0)
            *(half8*)(outg + ((size_t)b * 4096 + i * 64 + j) * 8) = vq;
    }
}

// ---------------------------------------------------------------------------
// K3: flash attention, split-K (SPLIT=4). Block = 64 queries (4 waves x 16),
// 16 key-tiles of 64. global_load_lds staging (linear LDS, pre-swizzled V
// source), 2-phase double buffer. log2-domain softmax + defer-max.
// Outputs fp16 partial acc + (m,l). grid 1024 = s*256 + b*64 + qt.
// ---------------------------------------------------------------------------
__global__ __launch_bounds__(256) void attn_kernel(
    const _Float16* __restrict__ Qg, const _Float16* __restrict__ Kg,
    const _Float16* __restrict__ Vg,
    _Float16* __restrict__ pacc, float* __restrict__ pml)
{
    __shared__ __align__(16) _Float16 smem[1024 + 8192]; // K[2][64][8], V[2][64][64]
    _Float16* K0 = smem;
    _Float16* V0 = smem + 1024;
    int tid = threadIdx.x, lane = tid & 63, w = tid >> 6;
    int q = lane & 15, g = lane >> 4;
    int bid = blockIdx.x;
    int qt = bid & 63, b = (bid >> 6) & 3, s = bid >> 8;
    int m0 = qt * 64 + w * 16;

    half8 qf = {};
    if (g == 0) {
        half8 qraw = *(const half8*)(Qg + ((size_t)b * 4096 + m0 + q) * 8);
#pragma unroll
        for (int j = 0; j < 8; j++) qf[j] = (_Float16)((float)qraw[j] * 1.44269504f);
    }
    const _Float16* Kbase = Kg + ((size_t)b * 4096 + s * 1024) * 8;
    const _Float16* Vbase = Vg + (size_t)b * 64 * 4096 + s * 1024;

    f32x4 acc[4] = {};
    float m_run = -1e30f, l_run = 0.f;
    const f32x4 zero4 = {};

    auto stage = [&](int buf, int t) {
        int n0 = t * 64;
#pragma unroll
        for (int ii = 0; ii < 2; ii++) {
            int c = w * 16 + ii * 8 + (lane >> 3);
            int slot = lane & 7;
            const _Float16* src = Vbase + (size_t)c * 4096 + n0 + ((slot ^ (c & 7)) << 3);
            _Float16* dstb = V0 + buf * 4096 + (w * 16 + ii * 8) * 64;
            gload16(src, dstb);
        }
        if (w == 0) {
            const _Float16* src = Kbase + (size_t)(n0 + lane) * 8;
            gload16(src, K0 + buf * 512);
        }
    };

    stage(0, 0);
    __syncthreads();
    int cur = 0;
    for (int t = 0; t < 16; t++) {
        if (t + 1 < 16) stage(cur ^ 1, t + 1);
        const _Float16* Kl = K0 + cur * 512;
        const _Float16* Vl = V0 + cur * 4096;

        f32x4 st[4];
#pragma unroll
        for (int mf = 0; mf < 4; mf++) {
            half8 af = {};
            if (g == 0) af = *(const half8*)(Kl + (mf * 16 + q) * 8);
            st[mf] = mfma16(af, qf, zero4);
        }
        float pm = -1e30f;
#pragma unroll
        for (int mf = 0; mf < 4; mf++)
#pragma unroll
            for (int r = 0; r < 4; r++) pm = fmaxf(pm, st[mf][r]);
        pm = fmaxf(pm, __shfl_xor(pm, 16));
        pm = fmaxf(pm, __shfl_xor(pm, 32));

        float p[16];
        float ls = 0.f;
        if (__all(pm <= m_run)) {
#pragma unroll
            for (int mf = 0; mf < 4; mf++)
#pragma unroll
                for (int r = 0; r < 4; r++) {
                    float e = exp2f(st[mf][r] - m_run);
                    p[mf * 4 + r] = e; ls += e;
                }
        } else {
            float mnew = fmaxf(m_run, pm);
            float rr = exp2f(m_run - mnew);
#pragma unroll
            for (int mf = 0; mf < 4; mf++)
#pragma unroll
                for (int r = 0; r < 4; r++) {
                    float e = exp2f(st[mf][r] - mnew);
                    p[mf * 4 + r] = e; ls += e;
                }
            l_run *= rr;
#pragma unroll
            for (int mf = 0; mf < 4; mf++) acc[mf] *= rr;
            m_run = mnew;
        }
        ls += __shfl_xor(ls, 16);
        ls += __shfl_xor(ls, 32);
        l_run += ls;

#pragma unroll
        for (int f = 0; f < 2; f++) {
            half8 pb;
#pragma unroll
            for (int j = 0; j < 8; j++)
                pb[j] = (_Float16)p[(2 * f + (j >> 2)) * 4 + (j & 3)];
            int kg0 = 4 * f + (g >> 1);
#pragma unroll
            for (int mfc = 0; mfc < 4; mfc++) {
                int c = mfc * 16 + q;
                const _Float16* row = Vl + c * 64 + (g & 1) * 4;
                int sw = q & 7;
                half4v a0 = *(const half4v*)(row + ((kg0 ^ sw) << 3));
                half4v a1 = *(const half4v*)(row + (((kg0 + 2) ^ sw) << 3));
                half8 av = __builtin_shufflevector(a0, a1, 0, 1, 2, 3, 4, 5, 6, 7);
                acc[mfc] = mfma16(av, pb, acc[mfc]);
            }
        }
        __syncthreads();
        cur ^= 1;
    }
    // write partials (no normalization here)
    size_t tbase = (size_t)bid * 4096;
    int qq = w * 16 + q;
#pragma unroll
    for (int mf = 0; mf < 4; mf++)
#pragma unroll
        for (int r = 0; r < 4; r++)
            pacc[tbase + (mf * 16 + g * 4 + r) * 64 + qq] = (_Float16)acc[mf][r];
    if (g == 0) {
        pml[bid * 128 + qq] = m_run;
        pml[bid * 128 + 64 + qq] = l_run;
    }
}

// ---------------------------------------------------------------------------
// K3b: combine split partials + fused z = ca_w1 * out + ca_b1. grid 256.
// ---------------------------------------------------------------------------
__global__ __launch_bounds__(256) void combine_kernel(
    const _Float16* __restrict__ pacc, const float* __restrict__ pml,
    const _Float16* __restrict__ ApackCA, const float* __restrict__ cb1,
    float* __restrict__ zg)
{
    int tid = threadIdx.x, lane = tid & 63, w = tid >> 6;
    int q = lane & 15, g = lane >> 4;
    int bid = blockIdx.x;
    int qt = bid & 63, b = bid >> 6;
    int qq = w * 16 + q;

    float ms[4], lsv[4];
#pragma unroll
    for (int s = 0; s < 4; s++) {
        int tile = s * 256 + bid;
        ms[s] = pml[tile * 128 + qq];
        lsv[s] = pml[tile * 128 + 64 + qq];
    }
    float M = fmaxf(fmaxf(ms[0], ms[1]), fmaxf(ms[2], ms[3]));
    float L = 0.f, wwv[4];
#pragma unroll
    for (int s = 0; s < 4; s++) { wwv[s] = exp2f(ms[s] - M); L += lsv[s] * wwv[s]; }
    float inv = 1.f / L;

    f32x4 accc[4] = {};
#pragma unroll
    for (int s = 0; s < 4; s++) {
        size_t tb = (size_t)(s * 256 + bid) * 4096;
#pragma unroll
        for (int mf = 0; mf < 4; mf++)
#pragma unroll
            for (int r = 0; r < 4; r++)
                accc[mf][r] += wwv[s] * (float)pacc[tb + (mf * 16 + g * 4 + r) * 64 + qq];
    }
    half8 ob[2];
#pragma unroll
    for (int f = 0; f < 2; f++)
#pragma unroll
        for (int j = 0; j < 8; j++)
            ob[f][j] = (_Float16)(accc[2 * f + (j >> 2)][j & 3] * inv);
    f32x4 zacc[4] = {};
#pragma unroll
    for (int f = 0; f < 2; f++)
#pragma unroll
        for (int mf2 = 0; mf2 < 4; mf2++) {
            half8 a3 = *(const half8*)(ApackCA + (f * 4 + mf2) * 512 + lane * 8);
            zacc[mf2] = mfma16(a3, ob[f], zacc[mf2]);
        }
    int m0 = qt * 64 + w * 16;
#pragma unroll
    for (int mf2 = 0; mf2 < 4; mf2++)
#pragma unroll
        for (int r = 0; r < 4; r++) {
            int cp = mf2 * 16 + g * 4 + r;
            zg[(size_t)(b * 64 + cp) * 4096 + m0 + q] = zacc[mf2][r] + cb1[cp];
        }
}

// ---------------------------------------------------------------------------
// K4: out = ca_w2 * relu(upsample2x(z)) + ca_b2 + x. Block = 4 rows x 64 px.
// ---------------------------------------------------------------------------
__global__ __launch_bounds__(256) void post_kernel(
    const float* __restrict__ zg, const float* __restrict__ xg,
    const _Float16* __restrict__ ApackW2K4, const float* __restrict__ cb2,
    float* __restrict__ outg)
{
    __shared__ float zt[4 * 34 * 68];
    int tid = threadIdx.x, lane = tid & 63, w = tid >> 6;
    int x0 = blockIdx.x * 64, y0 = blockIdx.y * 4, b = blockIdx.z;
    int r0 = 2 * (int)blockIdx.y - 1;
    int cbs = 32 * (int)blockIdx.x - 1;
    for (int idx = tid; idx < 8704; idx += 256) {
        int col = idx % 34;
        int t2 = idx / 34;
        int r = t2 & 3, cp = t2 >> 2;
        int zr = min(max(r0 + r, 0), 63);
        int zc = min(max(cbs + col, 0), 63);
        zt[(r * 34 + col) * 68 + cp] = zg[(size_t)(b * 64 + cp) * 4096 + zr * 64 + zc];
    }
    __syncthreads();

    int q = lane & 15, g = lane >> 4;
    int y = y0 + w;
    int ra = (w >> 1) + (w & 1);
    float wyA = (w & 1) ? 0.75f : 0.25f;
    float wyB = 1.f - wyA;
    f32x4 acc[4][4] = {};
#pragma unroll
    for (int f = 0; f < 2; f++) {
        half8 a[4];
#pragma unroll
        for (int mf = 0; mf < 4; mf++)
            a[mf] = *(const half8*)(ApackW2K4 + (f * 4 + mf) * 512 + lane * 8);
#pragma unroll
        for (int nf = 0; nf < 4; nf++) {
            int pxl = nf * 16 + q;
            int ca = (pxl >> 1) + (pxl & 1);
            float wxA = (pxl & 1) ? 0.75f : 0.25f;
            float wxB = 1.f - wxA;
            half8 bfrag;
#pragma unroll
            for (int qd = 0; qd < 2; qd++) {
                int cpb = f * 32 + g * 8 + qd * 4;
                const float* z00 = &zt[(ra * 34 + ca) * 68 + cpb];
                f32x4 v00 = *(const f32x4*)z00;
                f32x4 v01 = *(const f32x4*)(z00 + 68);
                f32x4 v10 = *(const f32x4*)(z00 + 34 * 68);
                f32x4 v11 = *(const f32x4*)(z00 + 34 * 68 + 68);
                f32x4 zu = (v00 * wxA + v01 * wxB) * wyA + (v10 * wxA + v11 * wxB) * wyB;
#pragma unroll
                for (int e = 0; e < 4; e++) bfrag[qd * 4 + e] = (_Float16)fmaxf(zu[e], 0.f);
            }
#pragma unroll
            for (int mf = 0; mf < 4; mf++) acc[mf][nf] = mfma16(a[mf], bfrag, acc[mf][nf]);
        }
    }
#pragma unroll
    for (int mf = 0; mf < 4; mf++)
#pragma unroll
        for (int r = 0; r < 4; r++) {
            int c = mf * 16 + g * 4 + r;
            float bb = cb2[c];
#pragma unroll
            for (int nf = 0; nf < 4; nf++) {
                size_t oidx = ((size_t)(b * 64 + c) * 128 + y) * 128 + x0 + nf * 16 + q;
                outg[oidx] = acc[mf][nf][r] + bb + xg[oidx];
            }
        }
}

// ---------------------------------------------------------------------------
extern "C" void kernel_launch(void* const* d_in, const int* in_sizes, int n_in,
                              void* d_out, int out_size, void* d_ws, size_t ws_size,
                              hipStream_t stream)
{
    const float* x    = (const float*)d_in[0];
    const float* mask = (const float*)d_in[1];
    const float* Wq   = (const float*)d_in[2];
    const float* bq   = (const float*)d_in[3];
    const float* Wk   = (const float*)d_in[4];
    const float* bk   = (const float*)d_in[5];
    const float* Wv   = (const float*)d_in[6];
    const float* bv   = (const float*)d_in[7];
    const float* a1   = (const float*)d_in[8];
    const float* a2   = (const float*)d_in[9];
    const float* mqw1 = (const float*)d_in[10];
    const float* mqb1 = (const float*)d_in[11];
    const float* mqw2 = (const float*)d_in[12];
    const float* mqb2 = (const float*)d_in[13];
    const float* mkw1 = (const float*)d_in[14];
    const float* mkb1 = (const float*)d_in[15];
    const float* mkw2 = (const float*)d_in[16];
    const float* mkb2 = (const float*)d_in[17];
    const float* caw1 = (const float*)d_in[18];
    const float* cab1 = (const float*)d_in[19];
    const float* caw2 = (const float*)d_in[20];
    const float* cab2 = (const float*)d_in[21];

    char* ws = (char*)d_ws;
    _Float16* ApackConv = (_Float16*)(ws + WS_APCONV);
    _Float16* ApackW2s  = (_Float16*)(ws + WS_APW2S);
    _Float16* ApackCA   = (_Float16*)(ws + WS_APCA);
    _Float16* ApackW2K4 = (_Float16*)(ws + WS_APW2K4);
    _Float16* packed    = (_Float16*)(ws + WS_PACKED);
    float*    maskq     = (float*)(ws + WS_MASKQ);
    float*    maskk     = (float*)(ws + WS_MASKK);
    _Float16* Qg16      = (_Float16*)(ws + WS_Q16);
    _Float16* Kg16      = (_Float16*)(ws + WS_K16);
    _Float16* Vb        = (_Float16*)(ws + WS_V16);
    float*    zb        = (float*)(ws + WS_ZB);
    _Float16* pacc      = (_Float16*)(ws + WS_PACC);
    float*    pml       = (float*)(ws + WS_PML);

    hipMemsetAsync(ws + WS_PACKED, 0, 8652800u, stream);
    prep_kernel<<<dim3(64), dim3(256), 0, stream>>>(
        mqw1, mkw1, mqw2, mkw2, caw1, caw2, ApackConv, ApackW2s, ApackCA, ApackW2K4);
    pack_mask_kernel<<<dim3(64, 8, 4), dim3(256), 0, stream>>>(mask, packed);
    conv_mask_kernel<<<dim3(2, 32, 8), dim3(256), 0, stream>>>(
        packed, ApackConv, ApackW2s, mqb1, mqb2, mkb1, mkb2, maskq, maskk);
    proj_kernel<<<dim3(256), dim3(256), 0, stream>>>(
        x, maskq, maskk, Wq, bq, Wk, bk, Wv, bv, a1, a2, Qg16, Kg16, Vb);
    attn_kernel<<<dim3(1024), dim3(256), 0, stream>>>(Qg16, Kg16, Vb, pacc, pml);
    combine_kernel<<<dim3(256), dim3(256), 0, stream>>>(pacc, pml, ApackCA, cab1, zb);
    post_kernel<<<dim3(2, 32, 4), dim3(256), 0, stream>>>(
        zb, x, ApackW2K4, cab2, (float*)d_out);
}